// Round 1
// baseline (367.519 us; speedup 1.0000x reference)
//
#include <hip/hip_runtime.h>
#include <hip/hip_bf16.h>

// y = x @ P,  P = gamma * (w_q w_k^T) (x^T x) w_v      (no softmax => associativity)
// All GEMMs in one "NT" form: C[m][n] = scale * sum_k A[m][k] * B[n][k]
// (both operands k-contiguous => MFMA fragments are 16B LDS vector reads)

typedef __attribute__((ext_vector_type(8))) short bf16x8;   // 8 x bf16 (4 VGPRs)
typedef __attribute__((ext_vector_type(4))) float f32x4;    // 4 x fp32 accum

#define BM 64
#define BN 64
#define BK 32
#define KP 40   // LDS row pitch in bf16 (80B, 16B-aligned, breaks power-of-2 bank stride)

template<bool A_F32, bool OUT_F32>
__global__ __launch_bounds__(256)
void gemm_nt(const void* __restrict__ Ap, const __hip_bfloat16* __restrict__ Bp,
             void* __restrict__ Cp, int M, int N, int K,
             long sA, long sB, long sC, float scale)
{
    __shared__ __hip_bfloat16 At[BM][KP];
    __shared__ __hip_bfloat16 Bt[BN][KP];

    const int bz = blockIdx.z;
    const int n0 = blockIdx.x * BN;
    const int m0 = blockIdx.y * BM;

    const int tid  = threadIdx.x;
    const int lane = tid & 63;
    const int wave = tid >> 6;
    const int wm = (wave & 1) * 32;   // wave's 32x32 quadrant of the 64x64 block tile
    const int wn = (wave >> 1) * 32;
    const int l16 = lane & 15;
    const int lq  = lane >> 4;        // 0..3

    // staging: each of 256 threads loads one 16B chunk (8 bf16) per operand tile
    const int srow = tid >> 2;        // 0..63
    const int skk  = (tid & 3) << 3;  // 0,8,16,24

    const __hip_bfloat16* Bb = Bp + (size_t)bz * sB;

    f32x4 acc00 = {0.f,0.f,0.f,0.f};
    f32x4 acc01 = acc00, acc10 = acc00, acc11 = acc00;

    for (int k0 = 0; k0 < K; k0 += BK) {
        if (A_F32) {
            const float* Ab = (const float*)Ap + (size_t)bz * sA;
            const float* s = Ab + (size_t)(m0 + srow) * K + (k0 + skk);
            float4 f0 = *(const float4*)s;
            float4 f1 = *(const float4*)(s + 4);
            union { __hip_bfloat16 h[8]; uint4 u; } t;
            t.h[0] = __float2bfloat16(f0.x); t.h[1] = __float2bfloat16(f0.y);
            t.h[2] = __float2bfloat16(f0.z); t.h[3] = __float2bfloat16(f0.w);
            t.h[4] = __float2bfloat16(f1.x); t.h[5] = __float2bfloat16(f1.y);
            t.h[6] = __float2bfloat16(f1.z); t.h[7] = __float2bfloat16(f1.w);
            *(uint4*)&At[srow][skk] = t.u;
        } else {
            const __hip_bfloat16* Ab = (const __hip_bfloat16*)Ap + (size_t)bz * sA;
            *(uint4*)&At[srow][skk] = *(const uint4*)(Ab + (size_t)(m0 + srow) * K + (k0 + skk));
        }
        *(uint4*)&Bt[srow][skk] = *(const uint4*)(Bb + (size_t)(n0 + srow) * K + (k0 + skk));
        __syncthreads();

        // MFMA fragments: A[m=lane&15][k=(lane>>4)*8+j], B mirrored (verified layouts)
        bf16x8 a0 = *(const bf16x8*)&At[wm + l16     ][lq * 8];
        bf16x8 a1 = *(const bf16x8*)&At[wm + 16 + l16][lq * 8];
        bf16x8 b0 = *(const bf16x8*)&Bt[wn + l16     ][lq * 8];
        bf16x8 b1 = *(const bf16x8*)&Bt[wn + 16 + l16][lq * 8];
        acc00 = __builtin_amdgcn_mfma_f32_16x16x32_bf16(a0, b0, acc00, 0, 0, 0);
        acc01 = __builtin_amdgcn_mfma_f32_16x16x32_bf16(a0, b1, acc01, 0, 0, 0);
        acc10 = __builtin_amdgcn_mfma_f32_16x16x32_bf16(a1, b0, acc10, 0, 0, 0);
        acc11 = __builtin_amdgcn_mfma_f32_16x16x32_bf16(a1, b1, acc11, 0, 0, 0);
        __syncthreads();
    }

    // epilogue: C/D layout col=lane&15, row=(lane>>4)*4+reg (m89/m91-verified)
    float* Cf = (float*)Cp;
    __hip_bfloat16* Ch = (__hip_bfloat16*)Cp;
    #pragma unroll
    for (int i = 0; i < 2; ++i) {
        #pragma unroll
        for (int j = 0; j < 2; ++j) {
            f32x4 a = (i == 0) ? (j == 0 ? acc00 : acc01)
                               : (j == 0 ? acc10 : acc11);
            const int row0 = m0 + wm + i * 16 + lq * 4;
            const int col  = n0 + wn + j * 16 + l16;
            #pragma unroll
            for (int r = 0; r < 4; ++r) {
                float v = a[r] * scale;
                size_t idx = (size_t)bz * sC + (size_t)(row0 + r) * N + col;
                if (OUT_F32) Cf[idx] = v;
                else         Ch[idx] = __float2bfloat16(v);
            }
        }
    }
}

// Tiled transpose + fp32->bf16 cast: in (R x C) fp32 row-major -> out (C x R) bf16
#define TP 64
__global__ __launch_bounds__(256)
void transpose_cast(const float* __restrict__ in, __hip_bfloat16* __restrict__ out,
                    int R, int C, long inStride, long outStride)
{
    __shared__ __hip_bfloat16 tile[TP][TP + 2];  // pitch 66 -> conflict-free column reads
    const int b  = blockIdx.z;
    const int r0 = blockIdx.x * TP;
    const int c0 = blockIdx.y * TP;
    const float* inb = in + (size_t)b * inStride;
    __hip_bfloat16* outb = out + (size_t)b * outStride;
    const int tx = threadIdx.x;   // 0..63
    const int ty = threadIdx.y;   // 0..3
    #pragma unroll
    for (int r = 0; r < TP; r += 4) {
        const int row = r + ty;
        tile[row][tx] = __float2bfloat16(inb[(size_t)(r0 + row) * C + c0 + tx]);
    }
    __syncthreads();
    #pragma unroll
    for (int r = 0; r < TP; r += 4) {
        const int row = r + ty;   // output row = input column c0+row
        outb[(size_t)(c0 + row) * R + r0 + tx] = tile[tx][row];
    }
}

__global__ __launch_bounds__(256)
void cast_f32_bf16(const float* __restrict__ in, __hip_bfloat16* __restrict__ out, int n)
{
    const int i = (blockIdx.x * 256 + threadIdx.x) << 2;
    if (i >= n) return;
    float4 f = *(const float4*)(in + i);
    union { __hip_bfloat16 h[4]; uint2 u; } t;
    t.h[0] = __float2bfloat16(f.x); t.h[1] = __float2bfloat16(f.y);
    t.h[2] = __float2bfloat16(f.z); t.h[3] = __float2bfloat16(f.w);
    *(uint2*)(out + i) = t.u;
}

extern "C" void kernel_launch(void* const* d_in, const int* in_sizes, int n_in,
                              void* d_out, int out_size, void* d_ws, size_t ws_size,
                              hipStream_t stream)
{
    const int Bz = 4, T = 4096, D = 1024;
    const float gamma = 32.0f;  // sqrt(1024)

    const float* x  = (const float*)d_in[0];
    const float* wq = (const float*)d_in[1];
    const float* wk = (const float*)d_in[2];
    const float* wv = (const float*)d_in[3];
    float* y = (float*)d_out;

    // workspace layout (32 MB total)
    unsigned char* p = (unsigned char*)d_ws;
    const size_t DD = (size_t)D * D;
    __hip_bfloat16* Gb  = (__hip_bfloat16*)p; p += Bz * DD * 2;   //  8 MB  G_b = x_b^T x_b
    __hip_bfloat16* Hb  = (__hip_bfloat16*)p; p += Bz * DD * 2;   //  8 MB  H_b = C0 G_b
    __hip_bfloat16* PTb = (__hip_bfloat16*)p; p += Bz * DD * 2;   //  8 MB  P_b^T
    __hip_bfloat16* wqb = (__hip_bfloat16*)p; p += DD * 2;        //  2 MB
    __hip_bfloat16* wkb = (__hip_bfloat16*)p; p += DD * 2;        //  2 MB
    __hip_bfloat16* wvT = (__hip_bfloat16*)p; p += DD * 2;        //  2 MB  w_v^T
    __hip_bfloat16* C0b = (__hip_bfloat16*)p; p += DD * 2;        //  2 MB  w_q w_k^T
    // x^T (bf16, B x D x T = 32 MB) staged in d_out's first half; consumed by the
    // G GEMM, then fully overwritten by the final y GEMM.
    __hip_bfloat16* xbT = (__hip_bfloat16*)d_out;

    dim3 blk(256);

    // casts / transposes
    cast_f32_bf16<<<dim3((int)(DD / 1024)), blk, 0, stream>>>(wq, wqb, (int)DD);
    cast_f32_bf16<<<dim3((int)(DD / 1024)), blk, 0, stream>>>(wk, wkb, (int)DD);
    transpose_cast<<<dim3(D / TP, D / TP, 1), dim3(64, 4), 0, stream>>>(wv, wvT, D, D, 0, 0);
    transpose_cast<<<dim3(T / TP, D / TP, Bz), dim3(64, 4), 0, stream>>>(
        x, xbT, T, D, (long)T * D, (long)D * T);

    // C0 = w_q w_k^T                      : NT(A=wq, B=wk)
    gemm_nt<false, false><<<dim3(D / BN, D / BM, 1), blk, 0, stream>>>(
        wqb, wkb, C0b, D, D, D, 0, 0, 0, 1.0f);
    // G_b = x_b^T x_b                     : NT(A=xbT, B=xbT), K = T
    gemm_nt<false, false><<<dim3(D / BN, D / BM, Bz), blk, 0, stream>>>(
        xbT, xbT, Gb, D, D, T, (long)D * T, (long)D * T, (long)DD, 1.0f);
    // H_b = C0 G_b  (G symmetric)         : NT(A=C0, B=G)
    gemm_nt<false, false><<<dim3(D / BN, D / BM, Bz), blk, 0, stream>>>(
        C0b, Gb, Hb, D, D, D, 0, (long)DD, (long)DD, 1.0f);
    // P_b^T = gamma * w_v^T H_b^T         : NT(A=wvT, B=H)  [C^T = NT(B,A)]
    gemm_nt<false, false><<<dim3(D / BN, D / BM, Bz), blk, 0, stream>>>(
        wvT, Hb, PTb, D, D, D, 0, (long)DD, (long)DD, gamma);
    // y_b = x_b P_b                       : NT(A=x fp32, B=P^T), out fp32
    gemm_nt<true, true><<<dim3(D / BN, T / BM, Bz), blk, 0, stream>>>(
        x, PTb, y, T, D, D, (long)T * D, (long)DD, (long)T * D, 1.0f);
}